// Round 1
// 445.067 us; speedup vs baseline: 1.0042x; 1.0042x over previous
//
#include <hip/hip_runtime.h>

// SEST: SE-gating + soft-threshold, fused single pass.
// inputs [B,F,E] f32, W1[F,R] W2[R,F] W3[F,R] W4[R,F], out [B,F,2E] f32.
// B=16384 F=39 E=64 R=13. Memory-bound: 491 MB total -> ~78us floor @6.3TB/s.
//
// v2: one WAVE per batch row (4 rows/block), zero barriers in the hot path.
//     All gating math is wave-local via shfl; x cached in regs between the
//     reduce pass and the output pass; weights staged to LDS once per block
//     (single barrier, overlapped with the phase-1 global loads).

#define SEST_B 16384
#define SEST_F 39
#define SEST_E 64
#define SEST_R 13
#define WPB    4          // waves (= batch rows) per block

__global__ __launch_bounds__(256, 4) void sest_kernel(
    const float* __restrict__ x,
    const float* __restrict__ W1,
    const float* __restrict__ W2,
    const float* __restrict__ W3,
    const float* __restrict__ W4,
    float* __restrict__ out)
{
    const int tid  = threadIdx.x;
    const int w    = tid >> 6;      // wave 0..3  -> batch row
    const int lane = tid & 63;
    const int g    = lane >> 4;     // 16-lane group 0..3 (one f-row per pass)
    const int s    = lane & 15;     // float4 slot within row (16*4 = 64 = E)
    const int b    = blockIdx.x * WPB + w;

    // ---- weights -> LDS (once per block; 8.1 KB, coalesced) ----
    __shared__ float sW1[SEST_F * SEST_R];
    __shared__ float sW2[SEST_R * SEST_F];
    __shared__ float sW3[SEST_F * SEST_R];
    __shared__ float sW4[SEST_R * SEST_F];
    for (int i = tid; i < SEST_F * SEST_R; i += 256) {
        sW1[i] = W1[i];
        sW2[i] = W2[i];
        sW3[i] = W3[i];
        sW4[i] = W4[i];
    }

    const float4* in4 = reinterpret_cast<const float4*>(x)
                        + (size_t)b * (SEST_F * (SEST_E / 4));

    // ---- phase 1: vector load (kept in regs) + per-row mean / abs-mean ----
    // pass i covers rows f = i*4+g (i=0..9 -> f=0..39, f=39 predicated off).
    // Wave reads 1 KB contiguous per pass (4 rows x 256 B) -- fully coalesced.
    float4 xr[10];
    float  zm[10], am[10];
    #pragma unroll
    for (int i = 0; i < 10; ++i) {
        const int f = i * 4 + g;
        float sx = 0.f, sa = 0.f;
        if (f < SEST_F) {
            const float4 v = in4[f * (SEST_E / 4) + s];
            xr[i] = v;
            sx = v.x + v.y + v.z + v.w;
            sa = fabsf(v.x) + fabsf(v.y) + fabsf(v.z) + fabsf(v.w);
        }
        // butterfly within the 16-lane group (masks <16 stay in-group):
        // afterwards every lane of the group holds the full row sum.
        #pragma unroll
        for (int m = 1; m < 16; m <<= 1) {
            sx += __shfl_xor(sx, m);
            sa += __shfl_xor(sa, m);
        }
        zm[i] = sx * (1.0f / 64.0f);   // Z[f]       (f = i*4 + my g)
        am[i] = sa * (1.0f / 64.0f);   // abs_mean[f]
    }

    __syncthreads();   // weights staged (only barrier; overlaps phase-1 above)

    // ---- layer 1: H1 = relu(Z@W1), H2 = relu(Am@W3) -------------------
    // Every lane computes output r = lane&15 (clamped); valid at r<13.
    // Z[f]/Am[f] gathered by broadcast-shfl from group f&3 (compile-time
    // register index under full unroll -> v_readlane, no LDS round-trip).
    const int rl = lane & 15;
    const int rc = (rl < SEST_R) ? rl : 0;
    float acc1 = 0.f, acc3 = 0.f;
    #pragma unroll
    for (int f = 0; f < SEST_F; ++f) {
        const float zf = __shfl(zm[f >> 2], (f & 3) << 4);
        const float af = __shfl(am[f >> 2], (f & 3) << 4);
        acc1 = fmaf(zf, sW1[f * SEST_R + rc], acc1);
        acc3 = fmaf(af, sW3[f * SEST_R + rc], acc3);
    }
    const float h1 = fmaxf(acc1, 0.f);   // H1[r] lives at lane r (r=0..12)
    const float h2 = fmaxf(acc3, 0.f);   // H2[r] lives at lane r

    // ---- layer 2: A2 = relu(H1@W2), thv = relu(H2@W4) ------------------
    // Lane f (0..38) computes both outputs for feature f.
    const int fc = (lane < SEST_F) ? lane : 0;
    float acc2 = 0.f, acc4 = 0.f;
    #pragma unroll
    for (int r = 0; r < SEST_R; ++r) {
        const float h1r = __shfl(h1, r);
        const float h2r = __shfl(h2, r);
        acc2 = fmaf(h1r, sW2[r * SEST_F + fc], acc2);
        acc4 = fmaf(h2r, sW4[r * SEST_F + fc], acc4);
    }
    const float a2v = fmaxf(acc2, 0.f);   // A2[f]            at lane f
    const float thv = fmaxf(acc4, 0.f);   // relu-part of Th  at lane f

    // ---- phase 3: V = x*gate ; R = sign(x)*max(|x|-thres,0) ------------
    // thres[f] = abs_mean[f] * thv[f]; this lane already holds am[i] for
    // exactly the rows f = i*4+g it writes.
    float4* out4 = reinterpret_cast<float4*>(out)
                   + (size_t)b * (SEST_F * (2 * SEST_E / 4));
    #pragma unroll
    for (int i = 0; i < 10; ++i) {
        const int f  = i * 4 + g;
        const float a2 = __shfl(a2v, f);          // per-lane src (bpermute)
        const float th = am[i] * __shfl(thv, f);  // f=39 only when predicated off
        if (f < SEST_F) {
            const float4 v = xr[i];
            float4 V, Rv;
            V.x = v.x * a2; V.y = v.y * a2; V.z = v.z * a2; V.w = v.w * a2;
            Rv.x = copysignf(fmaxf(fabsf(v.x) - th, 0.f), v.x);
            Rv.y = copysignf(fmaxf(fabsf(v.y) - th, 0.f), v.y);
            Rv.z = copysignf(fmaxf(fabsf(v.z) - th, 0.f), v.z);
            Rv.w = copysignf(fmaxf(fabsf(v.w) - th, 0.f), v.w);
            // row f of out = [V(64) | R(64)] = 32 float4; wave writes the
            // full 2 KB (rows i*4..i*4+3) contiguously.
            out4[f * 32 + s]      = V;
            out4[f * 32 + 16 + s] = Rv;
        }
    }
}

extern "C" void kernel_launch(void* const* d_in, const int* in_sizes, int n_in,
                              void* d_out, int out_size, void* d_ws, size_t ws_size,
                              hipStream_t stream) {
    const float* x  = (const float*)d_in[0];
    const float* W1 = (const float*)d_in[1];
    const float* W2 = (const float*)d_in[2];
    const float* W3 = (const float*)d_in[3];
    const float* W4 = (const float*)d_in[4];
    float* out = (float*)d_out;

    sest_kernel<<<SEST_B / WPB, 256, 0, stream>>>(x, W1, W2, W3, W4, out);
}